// Round 12
// baseline (3423.972 us; speedup 1.0000x reference)
//
#include <hip/hip_runtime.h>

// B=2048, T=96, D_IN=64, H=256, L=2, K=20
// R12: R11 + (1) role-split GEMM waves: waves 0-3 run GEMM1, waves 4-7 run GEMM0,
// each wave covers TWO 16-row m-tiles -> every LDS B-frag read feeds 2 MFMAs.
// LDS ds_read_b128 per CU per iter: 832 -> 416 (was ~4.2us/iter at max clock,
// the dominant identified cost). A-frags stream via 4-deep register window.
// (2) sync hidden: proj/CRPS moved to t=it-2 (data confirmed by PREVIOUS poll);
// arrive(flag[it]) -> proj/CRPS work -> poll(flag[it]) after. Detection latency
// and block skew overlap with ~3us of work. (3) h0 AND h1 rings = 4 (skew<=2).
// Exchange stays R11-style: relaxed agent atomics (sc-bit plain loads/stores,
// coalesced, no fences) -- proven correct (absmax 0.0).

typedef __attribute__((ext_vector_type(8))) short short8v;   // 8 x bf16
typedef __attribute__((ext_vector_type(4))) float f32x4;
typedef unsigned long long u64;
typedef union { u64 q[2]; short8v v; } frag_u;

#define HBUF 524288        // elems per H ring slot: 16 grp * 128 * 256
#define GSTRIDE 32768      // elems per group: 128*256

static __device__ __forceinline__ unsigned short f2bf(float f) {
  unsigned int u = __float_as_uint(f);
  u += 0x7fffu + ((u >> 16) & 1u);   // RNE
  return (unsigned short)(u >> 16);
}
static __device__ __forceinline__ float bf2f(unsigned short u) {
  return __uint_as_float(((unsigned int)u) << 16);
}
static __device__ __forceinline__ float sigf(float x) { return 1.f / (1.f + __expf(-x)); }
static __device__ __forceinline__ float tanhfast(float x) {
  float xc = fminf(fmaxf(x, -15.f), 15.f);
  float e = __expf(2.f * xc);
  return (e - 1.f) / (e + 1.f);
}
static __device__ __forceinline__ float softplusf(float x) {
  return (x > 0.f) ? (x + log1pf(expf(-x))) : log1pf(expf(x));
}
static __device__ __forceinline__ void st8_llc(unsigned short* p, u64 v) {
  __hip_atomic_store((u64*)p, v, __ATOMIC_RELAXED, __HIP_MEMORY_SCOPE_AGENT);
}
static __device__ __forceinline__ u64 ld8_llc(const unsigned short* p) {
  return __hip_atomic_load((const u64*)p, __ATOMIC_RELAXED, __HIP_MEMORY_SCOPE_AGENT);
}
static __device__ __forceinline__ short8v ldfrag_llc(const unsigned short* p) {
  frag_u u;
  u.q[0] = ld8_llc(p);
  u.q[1] = ld8_llc(p + 4);
  return u.v;
}
static __device__ __forceinline__ short8v pack8(float4 a, float4 b) {
  short8v r;
  r[0] = (short)f2bf(a.x); r[1] = (short)f2bf(a.y);
  r[2] = (short)f2bf(a.z); r[3] = (short)f2bf(a.w);
  r[4] = (short)f2bf(b.x); r[5] = (short)f2bf(b.y);
  r[6] = (short)f2bf(b.z); r[7] = (short)f2bf(b.w);
  return r;
}

// ---------------- prep: fragment-major per-slice weights, biases ----------------
__global__ void prep_kernel(const float* __restrict__ Wih0, const float* __restrict__ Whh0,
                            const float* __restrict__ Wih1, const float* __restrict__ Whh1,
                            const float* __restrict__ bih0, const float* __restrict__ bhh0,
                            const float* __restrict__ bih1, const float* __restrict__ bhh1,
                            const float* __restrict__ Wpb,  const float* __restrict__ Wpg,
                            unsigned short* __restrict__ W0, unsigned short* __restrict__ W1,
                            unsigned short* __restrict__ Wp,
                            float* __restrict__ bias0, float* __restrict__ bias1) {
  int i = blockIdx.x * 256 + threadIdx.x;
  if (i < 327680) {            // W0f: [s][g][kk(10)][lane(64)][8]
    int s = i / 20480, rem = i % 20480;
    int g = rem / 5120, rem2 = rem % 5120;
    int kk = rem2 >> 9, lane = (rem2 >> 3) & 63, e = rem2 & 7;
    int n = g * 256 + s * 16 + (lane & 15);
    int k = kk * 32 + (lane >> 4) * 8 + e;
    float v = (k < 64) ? Wih0[n * 64 + k] : Whh0[n * 256 + (k - 64)];
    W0[i] = f2bf(v);
    return;
  }
  i -= 327680;
  if (i < 524288) {            // W1f: [s][g][kk(16)][lane(64)][8]
    int s = i >> 15, rem = i & 32767;
    int g = rem >> 13, rem2 = rem & 8191;
    int kk = rem2 >> 9, lane = (rem2 >> 3) & 63, e = rem2 & 7;
    int n = g * 256 + s * 16 + (lane & 15);
    int k = kk * 32 + (lane >> 4) * 8 + e;
    float v = (k < 256) ? Wih1[n * 256 + k] : Whh1[n * 256 + (k - 256)];
    W1[i] = f2bf(v);
    return;
  }
  i -= 524288;
  if (i < 10752) {             // WpF: [21][512]
    int o = i >> 9, k = i & 511;
    float v = (o == 0) ? Wpb[k] : Wpg[(o - 1) * 512 + k];
    Wp[i] = f2bf(v);
    return;
  }
  i -= 10752;
  if (i < 1024) { bias0[i] = bih0[i] + bhh0[i]; return; }
  i -= 1024;
  if (i < 1024) { bias1[i] = bih1[i] + bhh1[i]; return; }
}

// ---------------- main persistent cooperative kernel ----------------
__global__ __launch_bounds__(512, 2) void lstm_crps_kernel(
    const float* __restrict__ X,      // [2048,96,64]
    const float* __restrict__ Y,      // [2048,96]
    const unsigned short* __restrict__ W0f,
    const unsigned short* __restrict__ W1f,
    const unsigned short* __restrict__ WpF,
    const float* __restrict__ bias0, const float* __restrict__ bias1,
    const float* __restrict__ bpb, const float* __restrict__ bpg,
    unsigned short* __restrict__ H0, unsigned short* __restrict__ H1,
    int* __restrict__ flags,
    float* __restrict__ out) {
  __shared__ __align__(16) unsigned short WL0[20480];    // 40KB
  __shared__ __align__(16) unsigned short WL1[32768];    // 64KB
  __shared__ __align__(16) unsigned short WpL[21 * 520]; // ~21KB bank-spread
  __shared__ __align__(16) unsigned short HT0[128 * 20]; // 5KB transpose tile
  __shared__ __align__(16) unsigned short HT1[128 * 20]; // 5KB
  __shared__ float PJ[8][22];
  __shared__ float bpgs[20];
  __shared__ float CB[8][24], KN[8][24];

  const int tid = threadIdx.x;
  const int w  = tid >> 6;
  const int l  = tid & 63;
  const int lr = l & 15;
  const int lg = l >> 4;
  const int bid = blockIdx.x;
  const int grp = (bid & 7) * 2 + ((bid >> 3) & 1);   // XCD-local groups (heuristic)
  const int s   = bid >> 4;                           // gate-row slice

  const int role = w >> 2;     // 0: GEMM1 waves, 1: GEMM0 waves
  const int u = w & 3;         // wave-within-role; m-tiles {2u, 2u+1}

  // ---- load weight slice into LDS (once)
  {
    const int4* src0 = (const int4*)(W0f + s * 20480);
    int4* dst0 = (int4*)WL0;
    for (int i = tid; i < 2560; i += 512) dst0[i] = src0[i];
    const int4* src1 = (const int4*)(W1f + s * 32768);
    int4* dst1 = (int4*)WL1;
    for (int i = tid; i < 4096; i += 512) dst1[i] = src1[i];
    for (int i = tid; i < 10752; i += 512) {
      int o = i >> 9, k = i & 511;
      WpL[o * 520 + k] = WpF[i];
    }
    if (tid < 20) bpgs[tid] = bpg[tid];
  }

  float bzr[4];
  {
    const float* bsrc = (role == 0) ? bias1 : bias0;
#pragma unroll
    for (int g = 0; g < 4; ++g) bzr[g] = bsrc[g * 256 + 16 * s + lr];
  }
  float cs[2][4] = {};     // c-state: role0 -> c1, role1 -> c0
  float lossacc = 0.f;
  const float bpbv = bpb[0];

  const size_t growA = (size_t)(grp * 128 + (2 * u) * 16 + lr);     // m=0 A row
  const size_t growB = (size_t)(grp * 128 + (2 * u + 1) * 16 + lr); // m=1 A row
  const float* xpA = X + growA * 96 * 64 + lg * 8;
  const float* xpB = X + growB * 96 * 64 + lg * 8;
  const int prow = tid >> 2, pcg = tid & 3;   // repack map

  __syncthreads();

  for (int it = 0; it <= 97; ++it) {
    const int tA = it - 1;     // GEMM1 / h1-publish timestep
    const int tB = it - 2;     // proj/CRPS timestep

    float yv = 0.f;
    if (tB >= 0 && tid < 8) yv = Y[(size_t)(grp * 128 + 8 * s + tid) * 96 + tB];

    if (role == 0) {
      // ---- GEMM1(tA): [h0(tA) | h1(tA-1)] @ W1^T -> h1(tA), 2 m-tiles
      if (tA >= 0 && tA <= 95) {
        const bool h1v = (tA >= 1);
        const unsigned short* h0pA = H0 + (size_t)(tA & 3) * HBUF + growA * 256 + lg * 8;
        const unsigned short* h0pB = H0 + (size_t)(tA & 3) * HBUF + growB * 256 + lg * 8;
        const unsigned short* h1pA = H1 + (size_t)((tA - 1) & 3) * HBUF + growA * 256 + lg * 8;
        const unsigned short* h1pB = H1 + (size_t)((tA - 1) & 3) * HBUF + growB * 256 + lg * 8;
        f32x4 acc[2][4];
#pragma unroll
        for (int m = 0; m < 2; ++m)
#pragma unroll
          for (int g = 0; g < 4; ++g) { f32x4 z = {0.f, 0.f, 0.f, 0.f}; acc[m][g] = z; }
        short8v win[2][4];
#pragma unroll
        for (int kk = 0; kk < 4; ++kk) {
          win[0][kk] = ldfrag_llc(h0pA + kk * 32);
          win[1][kk] = ldfrag_llc(h0pB + kk * 32);
        }
#pragma unroll
        for (int kk = 0; kk < 8; ++kk) {
          short8v a0 = win[0][kk & 3], a1 = win[1][kk & 3];
          if (kk < 4) {
            win[0][kk & 3] = ldfrag_llc(h0pA + (kk + 4) * 32);
            win[1][kk & 3] = ldfrag_llc(h0pB + (kk + 4) * 32);
          } else if (h1v) {
            win[0][kk & 3] = ldfrag_llc(h1pA + (kk - 4) * 32);
            win[1][kk & 3] = ldfrag_llc(h1pB + (kk - 4) * 32);
          }
#pragma unroll
          for (int g = 0; g < 4; ++g) {
            short8v b = *(const short8v*)&WL1[((g * 16 + kk) * 64 + l) * 8];
            acc[0][g] = __builtin_amdgcn_mfma_f32_16x16x32_bf16(a0, b, acc[0][g], 0, 0, 0);
            acc[1][g] = __builtin_amdgcn_mfma_f32_16x16x32_bf16(a1, b, acc[1][g], 0, 0, 0);
          }
        }
        if (h1v) {
#pragma unroll
          for (int kk = 8; kk < 16; ++kk) {
            short8v a0 = win[0][kk & 3], a1 = win[1][kk & 3];
            if (kk < 12) {
              win[0][kk & 3] = ldfrag_llc(h1pA + (kk - 4) * 32);
              win[1][kk & 3] = ldfrag_llc(h1pB + (kk - 4) * 32);
            }
#pragma unroll
            for (int g = 0; g < 4; ++g) {
              short8v b = *(const short8v*)&WL1[((g * 16 + kk) * 64 + l) * 8];
              acc[0][g] = __builtin_amdgcn_mfma_f32_16x16x32_bf16(a0, b, acc[0][g], 0, 0, 0);
              acc[1][g] = __builtin_amdgcn_mfma_f32_16x16x32_bf16(a1, b, acc[1][g], 0, 0, 0);
            }
          }
        }
        // cell 1 (2 m-tiles), outputs to HT1
#pragma unroll
        for (int m = 0; m < 2; ++m)
#pragma unroll
          for (int r = 0; r < 4; ++r) {
            int rowl = (2 * u + m) * 16 + lg * 4 + r;
            float cn = sigf(acc[m][1][r] + bzr[1]) * cs[m][r]
                     + sigf(acc[m][0][r] + bzr[0]) * tanhfast(acc[m][2][r] + bzr[2]);
            cs[m][r] = cn;
            float hn = sigf(acc[m][3][r] + bzr[3]) * tanhfast(cn);
            HT1[rowl * 20 + lr] = f2bf(hn);
          }
      }
    } else {
      // ---- GEMM0(it): [x(it) | h0(it-1)] @ W0^T -> h0(it), 2 m-tiles
      if (it <= 95) {
        const bool h0v = (it >= 1);
        short8v xf[2][2];
        {
          const float* xp = xpA + (size_t)it * 64;
          xf[0][0] = pack8(*(const float4*)xp, *(const float4*)(xp + 4));
          xf[0][1] = pack8(*(const float4*)(xp + 32), *(const float4*)(xp + 36));
          const float* xq = xpB + (size_t)it * 64;
          xf[1][0] = pack8(*(const float4*)xq, *(const float4*)(xq + 4));
          xf[1][1] = pack8(*(const float4*)(xq + 32), *(const float4*)(xq + 36));
        }
        const unsigned short* h0pA = H0 + (size_t)((it - 1) & 3) * HBUF + growA * 256 + lg * 8;
        const unsigned short* h0pB = H0 + (size_t)((it - 1) & 3) * HBUF + growB * 256 + lg * 8;
        f32x4 acc[2][4];
#pragma unroll
        for (int m = 0; m < 2; ++m)
#pragma unroll
          for (int g = 0; g < 4; ++g) { f32x4 z = {0.f, 0.f, 0.f, 0.f}; acc[m][g] = z; }
        short8v win[2][4];
        if (h0v) {
#pragma unroll
          for (int kk = 0; kk < 4; ++kk) {
            win[0][kk] = ldfrag_llc(h0pA + kk * 32);
            win[1][kk] = ldfrag_llc(h0pB + kk * 32);
          }
        }
#pragma unroll
        for (int kk = 0; kk < 2; ++kk)
#pragma unroll
          for (int g = 0; g < 4; ++g) {
            short8v b = *(const short8v*)&WL0[((g * 10 + kk) * 64 + l) * 8];
            acc[0][g] = __builtin_amdgcn_mfma_f32_16x16x32_bf16(xf[0][kk], b, acc[0][g], 0, 0, 0);
            acc[1][g] = __builtin_amdgcn_mfma_f32_16x16x32_bf16(xf[1][kk], b, acc[1][g], 0, 0, 0);
          }
        if (h0v) {
#pragma unroll
          for (int kk = 0; kk < 8; ++kk) {
            short8v a0 = win[0][kk & 3], a1 = win[1][kk & 3];
            if (kk < 4) {
              win[0][kk & 3] = ldfrag_llc(h0pA + (kk + 4) * 32);
              win[1][kk & 3] = ldfrag_llc(h0pB + (kk + 4) * 32);
            }
#pragma unroll
            for (int g = 0; g < 4; ++g) {
              short8v b = *(const short8v*)&WL0[((g * 10 + 2 + kk) * 64 + l) * 8];
              acc[0][g] = __builtin_amdgcn_mfma_f32_16x16x32_bf16(a0, b, acc[0][g], 0, 0, 0);
              acc[1][g] = __builtin_amdgcn_mfma_f32_16x16x32_bf16(a1, b, acc[1][g], 0, 0, 0);
            }
          }
        }
        // cell 0 (2 m-tiles), outputs to HT0
#pragma unroll
        for (int m = 0; m < 2; ++m)
#pragma unroll
          for (int r = 0; r < 4; ++r) {
            int rowl = (2 * u + m) * 16 + lg * 4 + r;
            float cn = sigf(acc[m][1][r] + bzr[1]) * cs[m][r]
                     + sigf(acc[m][0][r] + bzr[0]) * tanhfast(acc[m][2][r] + bzr[2]);
            cs[m][r] = cn;
            float hn = sigf(acc[m][3][r] + bzr[3]) * tanhfast(cn);
            HT0[rowl * 20 + lr] = f2bf(hn);
          }
      }
    }

    __syncthreads();   // HT tiles complete

    // ---- repack: LDS tile -> contiguous 8B LLC stores
    if (it <= 95) {
      u64 v = *(const u64*)&HT0[prow * 20 + pcg * 4];
      st8_llc(H0 + (size_t)(it & 3) * HBUF + grp * GSTRIDE + prow * 256 + 16 * s + pcg * 4, v);
    }
    if (tA >= 0 && tA <= 95) {
      u64 v = *(const u64*)&HT1[prow * 20 + pcg * 4];
      st8_llc(H1 + (size_t)(tA & 3) * HBUF + grp * GSTRIDE + prow * 256 + 16 * s + pcg * 4, v);
    }

    __syncthreads();   // drains stores (vmcnt0) before arrival
    if (tid == 0) {    // ARRIVE (poll comes after proj/CRPS)
      int* f = flags + (it * 16 + grp) * 32;
      __hip_atomic_fetch_add(f, 1, __ATOMIC_RELAXED, __HIP_MEMORY_SCOPE_AGENT);
    }

    // ---- proj + CRPS for tB (data confirmed by PREVIOUS iteration's poll)
    if (tB >= 0) {
      if (tid < 168) {   // o-major: 8 lanes share one o
        int o = tid >> 3, r = tid & 7;
        const unsigned short* h0p = H0 + (size_t)(tB & 3) * HBUF
                                    + (size_t)(grp * 128 + 8 * s + r) * 256;
        const unsigned short* h1p = H1 + (size_t)(tB & 3) * HBUF
                                    + (size_t)(grp * 128 + 8 * s + r) * 256;
        const unsigned short* wpo = &WpL[o * 520];
        float pa[4] = {0.f, 0.f, 0.f, 0.f};
#pragma unroll 4
        for (int cb = 0; cb < 64; ++cb) {
          u64 q0 = ld8_llc(h0p + cb * 4);
          u64 q1 = ld8_llc(h1p + cb * 4);
          short8v wv = *(const short8v*)(wpo + cb * 8);
          float a = 0.f;
#pragma unroll
          for (int e = 0; e < 4; ++e) {
            a += bf2f((unsigned short)(q0 >> (16 * e))) * bf2f((unsigned short)wv[2 * e])
               + bf2f((unsigned short)(q1 >> (16 * e))) * bf2f((unsigned short)wv[2 * e + 1]);
          }
          pa[cb & 3] += a;
        }
        PJ[r][o] = (pa[0] + pa[1]) + (pa[2] + pa[3]) + ((o == 0) ? bpbv : bpgs[o - 1]);
      }
      __syncthreads();

      if (tid < 8) {
        const int row = tid;
        const float y = yv;
        const float h = 0.05f;
        float beta0 = softplusf(PJ[row][0]);
        {  // pass 1: spline coeffs bb -> CB
          float gprev = beta0, brawprev = 0.f, ssum = 0.f, g19 = 0.f;
#pragma unroll
          for (int i2 = 0; i2 < 20; ++i2) {
            float gi = softplusf(PJ[row][1 + i2]);
            float braw = (gi - gprev) * 10.f;
            float bbv = (i2 == 0) ? braw : (braw - brawprev);
            if (i2 < 19) { ssum += bbv; CB[row][i2] = bbv; }
            gprev = gi; brawprev = braw; g19 = gi;
          }
          CB[row][19] = g19 - ssum;
        }
        {  // pass 2: knots via prefix sums
          float S0 = 0.f, S1 = 0.f, S2 = 0.f;
          KN[row][0] = 0.f;
#pragma unroll
          for (int i2 = 0; i2 < 19; ++i2) {
            float bbv = CB[row][i2];
            float fi = (float)i2;
            S0 += bbv; S1 += fi * bbv; S2 += fi * fi * bbv;
            float ip = (float)(i2 + 1);
            KN[row][i2 + 1] = ip * h * beta0 + h * h * (ip * ip * S0 - 2.f * ip * S1 + S2);
          }
        }
        float Aq = 0.f, Bk = 0.f, Ck = 0.f, crps3 = 0.f;
        float best = 1e30f; int amin = 0;
#pragma unroll
        for (int i2 = 0; i2 < 20; ++i2) {
          float knot = KN[row][i2];
          float bbv = CB[row][i2];
          float d = y - knot;
          float ad = fabsf(d);
          if (ad < best) { best = ad; amin = i2; }
          float alf = (d > 0.f) ? 1.f : 0.f;
          float ks = (float)i2 * h;
          float ab = alf * bbv;
          Aq += ab; Bk += ab * ks; Ck += ab * ks * ks;
          float om = 1.f - ks; float om2 = om * om;
          crps3 += bbv * (1.f / 6.f) * om2 * om2;
        }
        float Bc = beta0 - 2.f * Bk;
        float Cc = Ck - y;
        float disc = Bc * Bc - 4.f * Aq * Cc;
        bool az = (Aq == 0.f);
        bool qs = (!az) && (disc >= 0.f);
        float alpha;
        if (qs)      alpha = (-Bc + sqrtf(disc)) / (2.f * Aq);
        else if (az) alpha = -Cc / ((Bc == 0.f) ? 1.f : Bc);
        else         alpha = (float)amin * h;
        float crps4 = 0.f;
#pragma unroll
        for (int i2 = 0; i2 < 20; ++i2) {
          float knot = KN[row][i2];
          float bbv = CB[row][i2];
          float alf = ((y - knot) > 0.f) ? 1.f : 0.f;
          float am = alpha - (float)i2 * h;
          crps4 += alf * (2.f / 3.f) * bbv * am * am * am;
        }
        lossacc += (-y * (1.f - 2.f * alpha) + beta0 * (1.f / 3.f - alpha * alpha)
                    + crps3 - crps4);
      }
    }

    // ---- POLL (overlapped: others' arrivals propagated during proj/CRPS)
    if (tid == 0) {
      int* f = flags + (it * 16 + grp) * 32;
      while (__hip_atomic_load(f, __ATOMIC_RELAXED, __HIP_MEMORY_SCOPE_AGENT) < 16)
        __builtin_amdgcn_s_sleep(2);
    }
    __syncthreads();
  }

  // block reduction: lanes 0..7 of wave 0 hold loss
  if (w == 0) {
#pragma unroll
    for (int off = 4; off > 0; off >>= 1) lossacc += __shfl_down(lossacc, off, 64);
    if (l == 0) atomicAdd(out, lossacc * (1.f / 2048.f));
  }
}

extern "C" void kernel_launch(void* const* d_in, const int* in_sizes, int n_in,
                              void* d_out, int out_size, void* d_ws, size_t ws_size,
                              hipStream_t stream) {
  const float* X    = (const float*)d_in[0];
  const float* Y    = (const float*)d_in[1];
  const float* Wih0 = (const float*)d_in[2];
  const float* Whh0 = (const float*)d_in[3];
  const float* Wih1 = (const float*)d_in[4];
  const float* Whh1 = (const float*)d_in[5];
  const float* bih0 = (const float*)d_in[6];
  const float* bhh0 = (const float*)d_in[7];
  const float* bih1 = (const float*)d_in[8];
  const float* bhh1 = (const float*)d_in[9];
  const float* Wpb  = (const float*)d_in[10];
  const float* bpb  = (const float*)d_in[11];
  const float* Wpg  = (const float*)d_in[12];
  const float* bpg  = (const float*)d_in[13];

  char* ws = (char*)d_ws;
  unsigned short* W0f = (unsigned short*)(ws);                // 655,360
  unsigned short* W1f = (unsigned short*)(ws + 655360);       // 1,048,576
  unsigned short* WpF = (unsigned short*)(ws + 1703936);      // 21,504
  float* bias0 = (float*)(ws + 1725440);                      // 4,096
  float* bias1 = (float*)(ws + 1729536);                      // 4,096
  unsigned short* H0 = (unsigned short*)(ws + 1736704);       // 4 rings = 4,194,304
  unsigned short* H1 = (unsigned short*)(ws + 5931008);       // 4 rings = 4,194,304
  int* flags = (int*)(ws + 10125312);                         // 98*16*32*4 = 200,704

  hipMemsetAsync(d_out, 0, sizeof(float), stream);
  hipMemsetAsync(flags, 0, 200704, stream);
  prep_kernel<<<3378, 256, 0, stream>>>(Wih0, Whh0, Wih1, Whh1, bih0, bhh0, bih1, bhh1,
                                        Wpb, Wpg, W0f, W1f, WpF, bias0, bias1);

  float* outp = (float*)d_out;
  void* kargs[] = {(void*)&X, (void*)&Y, (void*)&W0f, (void*)&W1f, (void*)&WpF,
                   (void*)&bias0, (void*)&bias1, (void*)&bpb, (void*)&bpg,
                   (void*)&H0, (void*)&H1, (void*)&flags, (void*)&outp};
  hipLaunchCooperativeKernel((const void*)lstm_crps_kernel, dim3(256), dim3(512),
                             kargs, 0, stream);
}

// Round 13
// 1582.955 us; speedup vs baseline: 2.1630x; 2.1630x over previous
//
#include <hip/hip_runtime.h>

// B=2048, T=96, D_IN=64, H=256, L=2, K=20
// R13 = R10 (proven best, 2779us) + two serial-tail cuts:
//  (1) projection via MFMA: Wp prepacked to CONCAT hp layout ([h0(256)|h1(256)],
//      column remap c = k<256 ? 2k : 2(k-256)+1) fragment-major; proj = waves 0-1,
//      16 MFMA each, A-frags straight from H0/H1. Replaces the 168-thread scalar
//      dot product (~2240 VALU inst/thread, ~4.5k cy of the post-sync tail).
//  (2) branchless fast softplus (__expf+__logf) in CRPS (was libm log1pf/expf).
// Everything else IDENTICAL to R10: 16 slices x 16 XCD-local groups, coop launch,
// weights LDS-resident, single sync/iter {syncthreads; tid0: add(RELEASE), poll
// (RELAXED), fence(ACQUIRE)}, h0 ring-4 / h1 ring-2, direct 2B h-stores, bulk
// A-frag prefetch. R12's role-split REVERTED (it serialized LLC loads).

typedef __attribute__((ext_vector_type(8))) short short8v;   // 8 x bf16
typedef __attribute__((ext_vector_type(4))) float f32x4;

#define HBUF 524288        // elems per H ring slot: 16 grp * 128 * 256
#define GSTRIDE 32768      // elems per group: 128*256

static __device__ __forceinline__ unsigned short f2bf(float f) {
  unsigned int u = __float_as_uint(f);
  u += 0x7fffu + ((u >> 16) & 1u);   // RNE
  return (unsigned short)(u >> 16);
}
static __device__ __forceinline__ float sigf(float x) { return 1.f / (1.f + __expf(-x)); }
static __device__ __forceinline__ float tanhfast(float x) {
  float xc = fminf(fmaxf(x, -15.f), 15.f);
  float e = __expf(2.f * xc);
  return (e - 1.f) / (e + 1.f);
}
static __device__ __forceinline__ float softplusf(float x) {
  // branchless fast softplus: x>0 ? x + log(1+e^-x) : log(1+e^-|x|)
  float e = __expf(-fabsf(x));
  float l = __logf(1.f + e);
  return (x > 0.f) ? x + l : l;
}

// ---------------- prep: fragment-major per-slice weights, biases ----------------
// W0f[s][g][kk(10)][lane(64)][8], W1f[s][g][kk(16)][lane(64)][8]
// WpF[nt(2)][kk(16)][lane(64)][8]: o = nt*16+(lane&15), k = kk*32+(lane>>4)*8+e,
//   concat col k -> orig hp col c = (k<256) ? 2k : 2(k-256)+1
__global__ void prep_kernel(const float* __restrict__ Wih0, const float* __restrict__ Whh0,
                            const float* __restrict__ Wih1, const float* __restrict__ Whh1,
                            const float* __restrict__ bih0, const float* __restrict__ bhh0,
                            const float* __restrict__ bih1, const float* __restrict__ bhh1,
                            const float* __restrict__ Wpb,  const float* __restrict__ Wpg,
                            unsigned short* __restrict__ W0, unsigned short* __restrict__ W1,
                            unsigned short* __restrict__ Wp,
                            float* __restrict__ bias0, float* __restrict__ bias1) {
  int i = blockIdx.x * 256 + threadIdx.x;
  if (i < 327680) {            // W0f
    int s = i / 20480, rem = i % 20480;
    int g = rem / 5120, rem2 = rem % 5120;
    int kk = rem2 >> 9, lane = (rem2 >> 3) & 63, e = rem2 & 7;
    int n = g * 256 + s * 16 + (lane & 15);
    int k = kk * 32 + (lane >> 4) * 8 + e;
    float v = (k < 64) ? Wih0[n * 64 + k] : Whh0[n * 256 + (k - 64)];
    W0[i] = f2bf(v);
    return;
  }
  i -= 327680;
  if (i < 524288) {            // W1f
    int s = i >> 15, rem = i & 32767;
    int g = rem >> 13, rem2 = rem & 8191;
    int kk = rem2 >> 9, lane = (rem2 >> 3) & 63, e = rem2 & 7;
    int n = g * 256 + s * 16 + (lane & 15);
    int k = kk * 32 + (lane >> 4) * 8 + e;
    float v = (k < 256) ? Wih1[n * 256 + k] : Whh1[n * 256 + (k - 256)];
    W1[i] = f2bf(v);
    return;
  }
  i -= 524288;
  if (i < 16384) {             // WpF fragment-major concat
    int nt = i >> 13, rem = i & 8191;
    int kk = rem >> 9, lane = (rem >> 3) & 63, e = rem & 7;
    int o = nt * 16 + (lane & 15);
    int k = kk * 32 + (lane >> 4) * 8 + e;
    int c = (k < 256) ? (2 * k) : (2 * (k - 256) + 1);
    float v = (o == 0) ? Wpb[c] : (o <= 20 ? Wpg[(o - 1) * 512 + c] : 0.f);
    Wp[i] = f2bf(v);
    return;
  }
  i -= 16384;
  if (i < 1024) { bias0[i] = bih0[i] + bhh0[i]; return; }
  i -= 1024;
  if (i < 1024) { bias1[i] = bih1[i] + bhh1[i]; return; }
}

// ---------------- main persistent cooperative kernel ----------------
__global__ __launch_bounds__(512, 2) void lstm_crps_kernel(
    const float* __restrict__ X,      // [2048,96,64]
    const float* __restrict__ Y,      // [2048,96]
    const unsigned short* __restrict__ W0f,
    const unsigned short* __restrict__ W1f,
    const unsigned short* __restrict__ WpF,
    const float* __restrict__ bias0, const float* __restrict__ bias1,
    const float* __restrict__ bpb, const float* __restrict__ bpg,
    unsigned short* __restrict__ H0, unsigned short* __restrict__ H1,
    int* __restrict__ flags,
    float* __restrict__ out) {
  __shared__ __align__(16) unsigned short WL0[20480];   // 40KB
  __shared__ __align__(16) unsigned short WL1[32768];   // 64KB
  __shared__ __align__(16) unsigned short WpL[16384];   // 32KB fragment-major
  __shared__ float PJ[8][22];
  __shared__ float bpgs[20];
  __shared__ float CB[8][24], KN[8][24];

  const int tid = threadIdx.x;
  const int w  = tid >> 6;     // wave 0..7 = m-tile
  const int l  = tid & 63;
  const int lr = l & 15;
  const int lg = l >> 4;
  const int bid = blockIdx.x;
  const int grp = (bid & 7) * 2 + ((bid >> 3) & 1);   // XCD-local groups (heuristic)
  const int s   = bid >> 4;                           // gate-row slice

  // ---- load weight slice into LDS (once)
  {
    const int4* src0 = (const int4*)(W0f + s * 20480);
    int4* dst0 = (int4*)WL0;
    for (int i = tid; i < 2560; i += 512) dst0[i] = src0[i];
    const int4* src1 = (const int4*)(W1f + s * 32768);
    int4* dst1 = (int4*)WL1;
    for (int i = tid; i < 4096; i += 512) dst1[i] = src1[i];
    const int4* srcp = (const int4*)WpF;
    int4* dstp = (int4*)WpL;
    for (int i = tid; i < 2048; i += 512) dstp[i] = srcp[i];
    if (tid < 20) bpgs[tid] = bpg[tid];
  }

  float bz0[4], bz1[4];
#pragma unroll
  for (int g = 0; g < 4; ++g) {
    int n = g * 256 + 16 * s + lr;
    bz0[g] = bias0[n];
    bz1[g] = bias1[n];
  }
  float c0s[4] = {}, c1s[4] = {};
  float lossacc = 0.f;
  const float bpbv = bpb[0];

  const int myrow = grp * 128 + w * 16 + lr;          // A-frag row
  const float* xrowp = X + (size_t)myrow * 96 * 64 + lg * 8;

  __syncthreads();

  for (int it = 0; it <= 96; ++it) {
    const int tA = it - 1;     // timestep finished by GEMM1/proj this iter

    // ---- A-frag loads (all issued early, independent)
    short8v h0f[8], h1f[8];
    if (it >= 1) {
      const unsigned short* hp = H0 + (size_t)(tA & 3) * HBUF + (size_t)myrow * 256 + lg * 8;
#pragma unroll
      for (int kk = 0; kk < 8; ++kk) h0f[kk] = *(const short8v*)(hp + kk * 32);
    }
    if (it >= 2) {             // h1(it-2); (it-2)&1 == it&1
      const unsigned short* hp = H1 + (size_t)(it & 1) * HBUF + (size_t)myrow * 256 + lg * 8;
#pragma unroll
      for (int kk = 0; kk < 8; ++kk) h1f[kk] = *(const short8v*)(hp + kk * 32);
    }
    float4 xa0, xa1, xb0, xb1;
    if (it < 96) {
      const float* xp = xrowp + (size_t)it * 64;
      xa0 = *(const float4*)xp;        xa1 = *(const float4*)(xp + 4);
      xb0 = *(const float4*)(xp + 32); xb1 = *(const float4*)(xp + 36);
    }
    float yv = 0.f;
    if (it >= 1 && tid < 8) yv = Y[(size_t)(grp * 128 + 8 * s + tid) * 96 + tA];

    f32x4 acc[4];

    // ---- step a: GEMM1(tA) = [h0(tA) | h1(tA-1)] @ W1^T -> h1(tA)
    if (it >= 1) {
#pragma unroll
      for (int g = 0; g < 4; ++g) { f32x4 z = {0.f, 0.f, 0.f, 0.f}; acc[g] = z; }
#pragma unroll
      for (int kk = 0; kk < 8; ++kk)
#pragma unroll
        for (int g = 0; g < 4; ++g) {
          short8v b = *(const short8v*)&WL1[((g * 16 + kk) * 64 + l) * 8];
          acc[g] = __builtin_amdgcn_mfma_f32_16x16x32_bf16(h0f[kk], b, acc[g], 0, 0, 0);
        }
      if (it >= 2) {
#pragma unroll
        for (int kk = 0; kk < 8; ++kk)
#pragma unroll
          for (int g = 0; g < 4; ++g) {
            short8v b = *(const short8v*)&WL1[((g * 16 + 8 + kk) * 64 + l) * 8];
            acc[g] = __builtin_amdgcn_mfma_f32_16x16x32_bf16(h1f[kk], b, acc[g], 0, 0, 0);
          }
      }
      unsigned short* h1c = H1 + (size_t)(tA & 1) * HBUF + grp * GSTRIDE;
#pragma unroll
      for (int r = 0; r < 4; ++r) {
        int rowl = w * 16 + lg * 4 + r;
        float cn = sigf(acc[1][r] + bz1[1]) * c1s[r]
                 + sigf(acc[0][r] + bz1[0]) * tanhfast(acc[2][r] + bz1[2]);
        c1s[r] = cn;
        float hn = sigf(acc[3][r] + bz1[3]) * tanhfast(cn);
        h1c[rowl * 256 + 16 * s + lr] = f2bf(hn);
      }
    }

    // ---- step b: GEMM0(it) = [x(it) | h0(it-1)] @ W0^T -> h0(it)
    if (it < 96) {
#pragma unroll
      for (int g = 0; g < 4; ++g) { f32x4 z = {0.f, 0.f, 0.f, 0.f}; acc[g] = z; }
      {
        short8v a0;
        a0[0] = (short)f2bf(xa0.x); a0[1] = (short)f2bf(xa0.y);
        a0[2] = (short)f2bf(xa0.z); a0[3] = (short)f2bf(xa0.w);
        a0[4] = (short)f2bf(xa1.x); a0[5] = (short)f2bf(xa1.y);
        a0[6] = (short)f2bf(xa1.z); a0[7] = (short)f2bf(xa1.w);
#pragma unroll
        for (int g = 0; g < 4; ++g) {
          short8v b = *(const short8v*)&WL0[((g * 10 + 0) * 64 + l) * 8];
          acc[g] = __builtin_amdgcn_mfma_f32_16x16x32_bf16(a0, b, acc[g], 0, 0, 0);
        }
        short8v a1;
        a1[0] = (short)f2bf(xb0.x); a1[1] = (short)f2bf(xb0.y);
        a1[2] = (short)f2bf(xb0.z); a1[3] = (short)f2bf(xb0.w);
        a1[4] = (short)f2bf(xb1.x); a1[5] = (short)f2bf(xb1.y);
        a1[6] = (short)f2bf(xb1.z); a1[7] = (short)f2bf(xb1.w);
#pragma unroll
        for (int g = 0; g < 4; ++g) {
          short8v b = *(const short8v*)&WL0[((g * 10 + 1) * 64 + l) * 8];
          acc[g] = __builtin_amdgcn_mfma_f32_16x16x32_bf16(a1, b, acc[g], 0, 0, 0);
        }
      }
      if (it >= 1) {
#pragma unroll
        for (int kk = 0; kk < 8; ++kk)
#pragma unroll
          for (int g = 0; g < 4; ++g) {
            short8v b = *(const short8v*)&WL0[((g * 10 + 2 + kk) * 64 + l) * 8];
            acc[g] = __builtin_amdgcn_mfma_f32_16x16x32_bf16(h0f[kk], b, acc[g], 0, 0, 0);
          }
      }
      unsigned short* h0c = H0 + (size_t)(it & 3) * HBUF + grp * GSTRIDE;
#pragma unroll
      for (int r = 0; r < 4; ++r) {
        int rowl = w * 16 + lg * 4 + r;
        float cn = sigf(acc[1][r] + bz0[1]) * c0s[r]
                 + sigf(acc[0][r] + bz0[0]) * tanhfast(acc[2][r] + bz0[2]);
        c0s[r] = cn;
        float hn = sigf(acc[3][r] + bz0[3]) * tanhfast(cn);
        h0c[rowl * 256 + 16 * s + lr] = f2bf(hn);
      }
    }

    // ---- single sync: h1(tA) and h0(it) visible group-wide
    __syncthreads();     // drains all vmem stores (compiler waitcnt before barrier)
    if (tid == 0) {
      int* f = flags + (it * 16 + grp) * 32;   // private 128B line
      __hip_atomic_fetch_add(f, 1, __ATOMIC_RELEASE, __HIP_MEMORY_SCOPE_AGENT);
      while (__hip_atomic_load(f, __ATOMIC_RELAXED, __HIP_MEMORY_SCOPE_AGENT) < 16)
        __builtin_amdgcn_s_sleep(2);
      __builtin_amdgcn_fence(__ATOMIC_ACQUIRE, "agent");
    }
    __syncthreads();

    // ---- step c: projection (MFMA, waves 0-1) + CRPS for tA
    if (it >= 1) {
      if (w < 2) {
        const int nt = w;   // n-tile: cols nt*16 .. nt*16+15
        // A-frag rows: block's 8 batch rows (lr>=8 duplicates row lr&7, discarded)
        const size_t prow = (size_t)(grp * 128 + 8 * s + (lr & 7)) * 256 + lg * 8;
        const unsigned short* h0p = H0 + (size_t)(tA & 3) * HBUF + prow;
        const unsigned short* h1p = H1 + (size_t)(tA & 1) * HBUF + prow;
        short8v af[16];
#pragma unroll
        for (int kk = 0; kk < 8; ++kk) af[kk] = *(const short8v*)(h0p + kk * 32);
#pragma unroll
        for (int kk = 0; kk < 8; ++kk) af[8 + kk] = *(const short8v*)(h1p + kk * 32);
        f32x4 ap = {0.f, 0.f, 0.f, 0.f};
#pragma unroll
        for (int kk = 0; kk < 16; ++kk) {
          short8v b = *(const short8v*)&WpL[((nt * 16 + kk) * 64 + l) * 8];
          ap = __builtin_amdgcn_mfma_f32_16x16x32_bf16(af[kk], b, ap, 0, 0, 0);
        }
#pragma unroll
        for (int r = 0; r < 4; ++r) {
          int m = lg * 4 + r, o = nt * 16 + lr;
          if (m < 8 && o < 21)
            PJ[m][o] = ap[r] + ((o == 0) ? bpbv : bpgs[o - 1]);
        }
      }
      __syncthreads();

      if (tid < 8) {
        const int row = tid;
        const float y = yv;
        const float h = 0.05f;
        float beta0 = softplusf(PJ[row][0]);
        {  // pass 1: spline coeffs bb -> CB
          float gprev = beta0, brawprev = 0.f, ssum = 0.f, g19 = 0.f;
#pragma unroll
          for (int i2 = 0; i2 < 20; ++i2) {
            float gi = softplusf(PJ[row][1 + i2]);
            float braw = (gi - gprev) * 10.f;
            float bbv = (i2 == 0) ? braw : (braw - brawprev);
            if (i2 < 19) { ssum += bbv; CB[row][i2] = bbv; }
            gprev = gi; brawprev = braw; g19 = gi;
          }
          CB[row][19] = g19 - ssum;
        }
        {  // pass 2: knots via prefix sums
          float S0 = 0.f, S1 = 0.f, S2 = 0.f;
          KN[row][0] = 0.f;
#pragma unroll
          for (int i2 = 0; i2 < 19; ++i2) {
            float bbv = CB[row][i2];
            float fi = (float)i2;
            S0 += bbv; S1 += fi * bbv; S2 += fi * fi * bbv;
            float ip = (float)(i2 + 1);
            KN[row][i2 + 1] = ip * h * beta0 + h * h * (ip * ip * S0 - 2.f * ip * S1 + S2);
          }
        }
        float Aq = 0.f, Bk = 0.f, Ck = 0.f, crps3 = 0.f;
        float best = 1e30f; int amin = 0;
#pragma unroll
        for (int i2 = 0; i2 < 20; ++i2) {
          float knot = KN[row][i2];
          float bbv = CB[row][i2];
          float d = y - knot;
          float ad = fabsf(d);
          if (ad < best) { best = ad; amin = i2; }
          float alf = (d > 0.f) ? 1.f : 0.f;
          float ks = (float)i2 * h;
          float ab = alf * bbv;
          Aq += ab; Bk += ab * ks; Ck += ab * ks * ks;
          float om = 1.f - ks; float om2 = om * om;
          crps3 += bbv * (1.f / 6.f) * om2 * om2;
        }
        float Bc = beta0 - 2.f * Bk;
        float Cc = Ck - y;
        float disc = Bc * Bc - 4.f * Aq * Cc;
        bool az = (Aq == 0.f);
        bool qs = (!az) && (disc >= 0.f);
        float alpha;
        if (qs)      alpha = (-Bc + sqrtf(disc)) / (2.f * Aq);
        else if (az) alpha = -Cc / ((Bc == 0.f) ? 1.f : Bc);
        else         alpha = (float)amin * h;
        float crps4 = 0.f;
#pragma unroll
        for (int i2 = 0; i2 < 20; ++i2) {
          float knot = KN[row][i2];
          float bbv = CB[row][i2];
          float alf = ((y - knot) > 0.f) ? 1.f : 0.f;
          float am = alpha - (float)i2 * h;
          crps4 += alf * (2.f / 3.f) * bbv * am * am * am;
        }
        lossacc += (-y * (1.f - 2.f * alpha) + beta0 * (1.f / 3.f - alpha * alpha)
                    + crps3 - crps4);
      }
      // no trailing barrier: next PJ write is 2+ barriers away
    }
  }

  // block reduction: lanes 0..7 of wave 0 hold loss
  if (w == 0) {
#pragma unroll
    for (int off = 4; off > 0; off >>= 1) lossacc += __shfl_down(lossacc, off, 64);
    if (l == 0) atomicAdd(out, lossacc * (1.f / 2048.f));
  }
}

extern "C" void kernel_launch(void* const* d_in, const int* in_sizes, int n_in,
                              void* d_out, int out_size, void* d_ws, size_t ws_size,
                              hipStream_t stream) {
  const float* X    = (const float*)d_in[0];
  const float* Y    = (const float*)d_in[1];
  const float* Wih0 = (const float*)d_in[2];
  const float* Whh0 = (const float*)d_in[3];
  const float* Wih1 = (const float*)d_in[4];
  const float* Whh1 = (const float*)d_in[5];
  const float* bih0 = (const float*)d_in[6];
  const float* bhh0 = (const float*)d_in[7];
  const float* bih1 = (const float*)d_in[8];
  const float* bhh1 = (const float*)d_in[9];
  const float* Wpb  = (const float*)d_in[10];
  const float* bpb  = (const float*)d_in[11];
  const float* Wpg  = (const float*)d_in[12];
  const float* bpg  = (const float*)d_in[13];

  char* ws = (char*)d_ws;
  unsigned short* W0f = (unsigned short*)(ws);                // 655,360
  unsigned short* W1f = (unsigned short*)(ws + 655360);       // 1,048,576
  unsigned short* WpF = (unsigned short*)(ws + 1703936);      // 16384*2 = 32,768
  float* bias0 = (float*)(ws + 1736704);                      // 4,096
  float* bias1 = (float*)(ws + 1740800);                      // 4,096
  unsigned short* H0 = (unsigned short*)(ws + 1744896);       // 4 rings = 4,194,304
  unsigned short* H1 = (unsigned short*)(ws + 5939200);       // 2 rings = 2,097,152
  int* flags = (int*)(ws + 8036352);                          // 97*16*32*4 = 198,656

  hipMemsetAsync(d_out, 0, sizeof(float), stream);
  hipMemsetAsync(flags, 0, 198656, stream);
  prep_kernel<<<3400, 256, 0, stream>>>(Wih0, Whh0, Wih1, Whh1, bih0, bhh0, bih1, bhh1,
                                        Wpb, Wpg, W0f, W1f, WpF, bias0, bias1);

  float* outp = (float*)d_out;
  void* kargs[] = {(void*)&X, (void*)&Y, (void*)&W0f, (void*)&W1f, (void*)&WpF,
                   (void*)&bias0, (void*)&bias1, (void*)&bpb, (void*)&bpg,
                   (void*)&H0, (void*)&H1, (void*)&flags, (void*)&outp};
  hipLaunchCooperativeKernel((const void*)lstm_crps_kernel, dim3(256), dim3(512),
                             kargs, 0, stream);
}